// Round 5
// baseline (458.493 us; speedup 1.0000x reference)
//
#include <hip/hip_runtime.h>

typedef float floatx4 __attribute__((ext_vector_type(4)));
typedef short short8 __attribute__((ext_vector_type(8)));

#define HIDDEN 2048
#define NH 16
#define NKV 4
#define HD 128
#define NB 2
#define SEQ 2048
#define MT (NB * SEQ)  // 4096

__device__ __forceinline__ unsigned short f2bf(float x) {
  union { float f; unsigned u; } v; v.f = x;
  unsigned r = v.u + 0x7FFFu + ((v.u >> 16) & 1u);  // RNE
  return (unsigned short)(r >> 16);
}

// ---------------- contiguous fp32 -> bf16 cast ----------------
__global__ void cast_bf16_kernel(const float* __restrict__ in,
                                 unsigned short* __restrict__ out, int n4) {
  int i = blockIdx.x * 256 + threadIdx.x;
  if (i >= n4) return;
  float4 v = ((const float4*)in)[i];
  ushort4 o;
  o.x = f2bf(v.x); o.y = f2bf(v.y); o.z = f2bf(v.z); o.w = f2bf(v.w);
  ((ushort4*)out)[i] = o;
}

// ------- transpose + cast: W[Kd][Nd] fp32 -> Wt[Nd][Kd] bf16 -------
__global__ void transpose_bf16_kernel(const float* __restrict__ W,
                                      unsigned short* __restrict__ Wt,
                                      int Kd, int Nd) {
  __shared__ float tile[32][33];
  int n0 = blockIdx.x * 32, k0 = blockIdx.y * 32;
  int tx = threadIdx.x, ty = threadIdx.y;
  for (int i = 0; i < 32; i += 8)
    tile[ty + i][tx] = W[(size_t)(k0 + ty + i) * Nd + n0 + tx];
  __syncthreads();
  for (int i = 0; i < 32; i += 8)
    Wt[(size_t)(n0 + ty + i) * Kd + k0 + tx] = f2bf(tile[tx][ty + i]);
}

// ------- C[M][N] fp32 = A[M][K] bf16 @ Bt[N][K]^T bf16 -------
// m97 structure: 128x128 tile, BK=32, 4 waves 2x2, 16x16x32 MFMA,
// global_load_lds width-16 staging into UNPADDED [128][32] LDS tiles.
__global__ __launch_bounds__(256, 3)
void gemm_bf16_kernel(const unsigned short* __restrict__ A,
                      const unsigned short* __restrict__ Bt,
                      float* __restrict__ C, int M, int N, int K) {
  __shared__ unsigned short As[128 * 32];
  __shared__ unsigned short Bs[128 * 32];
  const int tid = threadIdx.x;
  const int wave = tid >> 6, lane = tid & 63;
  const int quad = lane >> 4, l16 = lane & 15;
  const int m0 = blockIdx.x * 128, n0 = blockIdx.y * 128;
  const int wm = (wave >> 1) * 64, wn = (wave & 1) * 64;
  const int srow = lane >> 2;
  const int scol = (lane & 3) * 8;

  floatx4 acc[4][4] = {};

  for (int kt = 0; kt < K; kt += 32) {
    __syncthreads();
#pragma unroll
    for (int t = 0; t < 2; ++t) {
      int q = wave * 2 + t;
      int row = q * 16 + srow;
      __builtin_amdgcn_global_load_lds(
          (const __attribute__((address_space(1))) unsigned int*)&A[(size_t)(m0 + row) * K + kt + scol],
          (__attribute__((address_space(3))) unsigned int*)&As[q * 16 * 32],
          16, 0, 0);
      __builtin_amdgcn_global_load_lds(
          (const __attribute__((address_space(1))) unsigned int*)&Bt[(size_t)(n0 + row) * K + kt + scol],
          (__attribute__((address_space(3))) unsigned int*)&Bs[q * 16 * 32],
          16, 0, 0);
    }
    __syncthreads();
    short8 af[4], bf[4];
#pragma unroll
    for (int i = 0; i < 4; i++)
      af[i] = *(const short8*)&As[(wm + i * 16 + l16) * 32 + quad * 8];
#pragma unroll
    for (int j = 0; j < 4; j++)
      bf[j] = *(const short8*)&Bs[(wn + j * 16 + l16) * 32 + quad * 8];
#pragma unroll
    for (int i = 0; i < 4; i++)
#pragma unroll
      for (int j = 0; j < 4; j++)
        acc[i][j] = __builtin_amdgcn_mfma_f32_16x16x32_bf16(af[i], bf[j], acc[i][j], 0, 0, 0);
  }
#pragma unroll
  for (int i = 0; i < 4; i++) {
    int row = m0 + wm + i * 16 + quad * 4;
#pragma unroll
    for (int j = 0; j < 4; j++) {
      int col = n0 + wn + j * 16 + l16;
#pragma unroll
      for (int r = 0; r < 4; r++)
        C[(size_t)(row + r) * N + col] = acc[i][j][r];
    }
  }
}

// ------- per-head RMSNorm + RoPE + cast, X[MT][Nh*HD] fp32 -> out[NB][Nh][SEQ][HD] bf16 -------
__global__ void norm_rope_kernel(const float* __restrict__ X,
                                 const float* __restrict__ w,
                                 const float* __restrict__ cosb,
                                 const float* __restrict__ sinb,
                                 unsigned short* __restrict__ out, int Nh) {
  int rid = blockIdx.x * 4 + (threadIdx.x >> 6);
  int lane = threadIdx.x & 63;
  int m = rid / Nh, h = rid - m * Nh;
  int b = m / SEQ, s = m - b * SEQ;
  const float* x = X + (size_t)m * (Nh * HD) + h * HD;
  float x0 = x[lane], x1 = x[lane + 64];
  float ssq = x0 * x0 + x1 * x1;
#pragma unroll
  for (int off = 32; off >= 1; off >>= 1) ssq += __shfl_xor(ssq, off, 64);
  float rr = rsqrtf(ssq * (1.0f / 128.0f) + 1e-6f);
  float xn0 = x0 * rr * w[lane];
  float xn1 = x1 * rr * w[lane + 64];
  float c0 = cosb[s * HD + lane], c1 = cosb[s * HD + lane + 64];
  float s0 = sinb[s * HD + lane], s1 = sinb[s * HD + lane + 64];
  unsigned short* op = out + (size_t)((b * Nh + h) * SEQ + s) * HD;
  op[lane] = f2bf(xn0 * c0 - xn1 * s0);       // d < 64:  x*c - x[d+64]*s
  op[lane + 64] = f2bf(xn1 * c1 + xn0 * s1);  // d >= 64: x*c + x[d-64]*s
}

// ------- V transpose + cast (tiled, coalesced): Vraw[MT][NKV*HD] fp32 -> Vt[NB][NKV][HD][SEQ] bf16 -------
__global__ void v_transpose_kernel(const float* __restrict__ Vraw,
                                   unsigned short* __restrict__ Vt) {
  __shared__ float tile[32][33];
  int d0 = blockIdx.x * 32;   // 4 blocks over HD
  int s0 = blockIdx.y * 32;   // 64 blocks over SEQ
  int bkv = blockIdx.z;       // 8: b*NKV+kv
  int b = bkv >> 2, kv = bkv & 3;
  int tx = threadIdx.x, ty = threadIdx.y;
  const float* src = Vraw + (size_t)(b * SEQ + s0) * (NKV * HD) + kv * HD + d0;
  for (int i = 0; i < 32; i += 8)
    tile[ty + i][tx] = src[(size_t)(ty + i) * (NKV * HD) + tx];  // coalesced over d
  __syncthreads();
  unsigned short* dst = Vt + (size_t)(bkv * HD + d0) * SEQ + s0;
  for (int i = 0; i < 32; i += 8)
    dst[(size_t)(ty + i) * SEQ + tx] = f2bf(tile[tx][ty + i]);   // coalesced over s
}

// ------- flash attention, GQA, causal -------
// q-tile 128, 4 waves, each wave owns 32 q-rows (i=2 register blocking so each
// B-fragment LDS read feeds 2 MFMAs). Q A-frags preloaded to registers (no Q LDS).
// kv tiles of 128. 512 blocks; perm pairs co-resident blocks to equal work.
#define LQ 136  // LDS stride for [*][128] bf16 tiles (272B rows, 2-way alias = free)

__global__ __launch_bounds__(256, 2)
void attn_kernel(const unsigned short* __restrict__ Q,   // [NB][NH][SEQ][HD]
                 const unsigned short* __restrict__ Kb,  // [NB][NKV][SEQ][HD]
                 const unsigned short* __restrict__ Vt,  // [NB][NKV][HD][SEQ]
                 unsigned short* __restrict__ O) {       // [MT][NH*HD]
  __shared__ unsigned short KVs[128 * LQ];  // K-tile [kv=128][d=128] / V-tile [d=128][kv=128]
  __shared__ unsigned short Ps[128 * LQ];   // P [q=128][kv=128]
  const int tid = threadIdx.x;
  const int wave = tid >> 6, lane = tid & 63;
  const int quad = lane >> 4, l16 = lane & 15;
  // pairing permutation: perm[g] + perm[g+8] == 15 so block c and c+256 (likely
  // co-resident under linear dispatch) carry equal total work.
  const int permv[16] = {15, 1, 13, 3, 11, 5, 9, 7, 0, 14, 2, 12, 4, 10, 6, 8};
  const int qt = permv[blockIdx.x >> 5];
  const int bh = blockIdx.x & 31;
  const int b = bh >> 4, h = bh & 15, kvh = h >> 2;
  const int q0 = qt * 128;
  const int nkt = qt + 1;  // number of 128-wide kv tiles

  // preload Q fragments: wave rows wave*32 + i*16 + l16, k-chunk ks*32 + quad*8
  const unsigned short* Qg = Q + (size_t)((b * NH + h) * SEQ + q0) * HD;
  short8 qf[2][4];
#pragma unroll
  for (int i = 0; i < 2; ++i)
#pragma unroll
    for (int ks = 0; ks < 4; ++ks)
      qf[i][ks] = *(const short8*)&Qg[(size_t)(wave * 32 + i * 16 + l16) * HD + ks * 32 + quad * 8];

  floatx4 oacc[2][8] = {};
  float mrow[2][4], lrow[2][4];
#pragma unroll
  for (int i = 0; i < 2; ++i)
#pragma unroll
    for (int r = 0; r < 4; ++r) { mrow[i][r] = -1e30f; lrow[i][r] = 0.f; }
  const float scale = 0.08838834764831845f;  // 1/sqrt(128)
  const unsigned short* Kg0 = Kb + (size_t)((b * NKV + kvh) * SEQ) * HD;
  const unsigned short* Vg0 = Vt + (size_t)((b * NKV + kvh) * HD) * SEQ;

  for (int kt = 0; kt < nkt; ++kt) {
    __syncthreads();  // prev PV reads of KVs done
    // stage K tile: 128 rows x 128 bf16 = 2048 x 16B
    for (int c = tid; c < 2048; c += 256) {
      int r = c >> 4, c8 = c & 15;
      *(uint4*)&KVs[r * LQ + c8 * 8] = *(const uint4*)&Kg0[(size_t)(kt * 128 + r) * HD + c8 * 8];
    }
    __syncthreads();
    // S = Q @ K^T : wave rows wave*32..+31 (i=2), cols 0..127
    floatx4 sc[2][8] = {};
#pragma unroll
    for (int ks = 0; ks < 4; ++ks) {
#pragma unroll
      for (int j = 0; j < 8; ++j) {
        short8 bfr = *(const short8*)&KVs[(j * 16 + l16) * LQ + ks * 32 + quad * 8];
#pragma unroll
        for (int i = 0; i < 2; ++i)
          sc[i][j] = __builtin_amdgcn_mfma_f32_16x16x32_bf16(qf[i][ks], bfr, sc[i][j], 0, 0, 0);
      }
    }
#pragma unroll
    for (int i = 0; i < 2; ++i)
#pragma unroll
      for (int j = 0; j < 8; ++j)
#pragma unroll
        for (int r = 0; r < 4; ++r) sc[i][j][r] *= scale;
    if (kt == qt) {  // diagonal tile: causal mask (kv base == q0)
#pragma unroll
      for (int i = 0; i < 2; ++i) {
        int rowl = wave * 32 + i * 16 + quad * 4;
#pragma unroll
        for (int j = 0; j < 8; ++j) {
          int col = j * 16 + l16;
#pragma unroll
          for (int r = 0; r < 4; ++r)
            if (col > rowl + r) sc[i][j][r] = -1e30f;
        }
      }
    }
    // online softmax; each row lives in a 16-lane group
    float alp[2][4];
#pragma unroll
    for (int i = 0; i < 2; ++i) {
#pragma unroll
      for (int r = 0; r < 4; ++r) {
        float mx = sc[i][0][r];
#pragma unroll
        for (int j = 1; j < 8; ++j) mx = fmaxf(mx, sc[i][j][r]);
#pragma unroll
        for (int off = 1; off < 16; off <<= 1) mx = fmaxf(mx, __shfl_xor(mx, off, 64));
        float mn = fmaxf(mrow[i][r], mx);
        alp[i][r] = __expf(mrow[i][r] - mn);
        mrow[i][r] = mn;
        float rs = 0.f;
#pragma unroll
        for (int j = 0; j < 8; ++j) {
          float p = __expf(sc[i][j][r] - mn);
          sc[i][j][r] = p;
          rs += p;
        }
#pragma unroll
        for (int off = 1; off < 16; off <<= 1) rs += __shfl_xor(rs, off, 64);
        lrow[i][r] = lrow[i][r] * alp[i][r] + rs;
      }
    }
#pragma unroll
    for (int i = 0; i < 2; ++i)
#pragma unroll
      for (int t = 0; t < 8; ++t)
#pragma unroll
        for (int r = 0; r < 4; ++r) oacc[i][t][r] *= alp[i][r];
    // P (C-layout) -> LDS -> A-layout; each wave writes its own 32 rows
#pragma unroll
    for (int i = 0; i < 2; ++i)
#pragma unroll
      for (int j = 0; j < 8; ++j)
#pragma unroll
        for (int r = 0; r < 4; ++r)
          Ps[(wave * 32 + i * 16 + quad * 4 + r) * LQ + j * 16 + l16] = f2bf(sc[i][j][r]);
    __syncthreads();  // all waves' K reads done before V overwrites KVs
    // stage V tile as [d=128][kv=128] = 2048 x 16B
    for (int c = tid; c < 2048; c += 256) {
      int d = c >> 4, c8 = c & 15;
      *(uint4*)&KVs[d * LQ + c8 * 8] = *(const uint4*)&Vg0[(size_t)d * SEQ + kt * 128 + c8 * 8];
    }
    __syncthreads();
    // O += P @ V  (kv is the K-dim, 128 = 4 x 32); wave reads its own P rows
#pragma unroll
    for (int ks = 0; ks < 4; ++ks) {
      short8 afr[2];
#pragma unroll
      for (int i = 0; i < 2; ++i)
        afr[i] = *(const short8*)&Ps[(wave * 32 + i * 16 + l16) * LQ + ks * 32 + quad * 8];
#pragma unroll
      for (int t = 0; t < 8; ++t) {
        short8 bfr = *(const short8*)&KVs[(t * 16 + l16) * LQ + ks * 32 + quad * 8];
#pragma unroll
        for (int i = 0; i < 2; ++i)
          oacc[i][t] = __builtin_amdgcn_mfma_f32_16x16x32_bf16(afr[i], bfr, oacc[i][t], 0, 0, 0);
      }
    }
  }
  float inv[2][4];
#pragma unroll
  for (int i = 0; i < 2; ++i)
#pragma unroll
    for (int r = 0; r < 4; ++r) inv[i][r] = 1.0f / lrow[i][r];
#pragma unroll
  for (int i = 0; i < 2; ++i)
#pragma unroll
    for (int t = 0; t < 8; ++t) {
      int col = h * HD + t * 16 + l16;
#pragma unroll
      for (int r = 0; r < 4; ++r) {
        int row = q0 + wave * 32 + i * 16 + quad * 4 + r;
        O[(size_t)(b * SEQ + row) * (NH * HD) + col] = f2bf(oacc[i][t][r] * inv[i][r]);
      }
    }
}

extern "C" void kernel_launch(void* const* d_in, const int* in_sizes, int n_in,
                              void* d_out, int out_size, void* d_ws, size_t ws_size,
                              hipStream_t stream) {
  const float* hidden = (const float*)d_in[0];
  const float* cosb   = (const float*)d_in[1];
  const float* sinb   = (const float*)d_in[2];
  const float* Wq     = (const float*)d_in[3];
  const float* Wk     = (const float*)d_in[4];
  const float* Wv     = (const float*)d_in[5];
  const float* Wo     = (const float*)d_in[6];
  const float* qw     = (const float*)d_in[7];
  const float* kw     = (const float*)d_in[8];
  (void)in_sizes; (void)n_in; (void)out_size; (void)ws_size;

  char* ws = (char*)d_ws;
  size_t off = 0;
  auto alloc = [&](size_t n) { char* p = ws + off; off += (n + 255) & ~(size_t)255; return p; };

  unsigned short* hb  = (unsigned short*)alloc((size_t)MT * HIDDEN * 2);  // hidden bf16 (16 MB)
  unsigned short* wqt = (unsigned short*)alloc((size_t)2048 * 2048 * 2);  // Wq^T bf16 [N][K] (8 MB)
  unsigned short* wkt = (unsigned short*)alloc((size_t)512 * 2048 * 2);   // (2 MB)
  unsigned short* wvt = (unsigned short*)alloc((size_t)512 * 2048 * 2);   // (2 MB)
  unsigned short* wot = (unsigned short*)alloc((size_t)2048 * 2048 * 2);  // (8 MB)
  float* kraw = (float*)alloc((size_t)MT * 512 * 4);                      // (8 MB)
  float* vraw = (float*)alloc((size_t)MT * 512 * 4);                      // (8 MB)
  unsigned short* Qb  = (unsigned short*)alloc((size_t)MT * 2048 * 2);  // [NB][NH][SEQ][HD] (16 MB)
  unsigned short* Kbb = (unsigned short*)alloc((size_t)MT * 512 * 2);   // [NB][NKV][SEQ][HD] (4 MB)
  unsigned short* Vtb = (unsigned short*)alloc((size_t)MT * 512 * 2);   // [NB][NKV][HD][SEQ] (4 MB)
  unsigned short* Ob  = (unsigned short*)alloc((size_t)MT * 2048 * 2);  // attn out [MT][NH*HD] (16 MB)
  // d_out (32 MB fp32) doubles as Q-GEMM scratch; consumed by norm_rope(Q)
  // before the final GEMM overwrites it. Peak ws ~= 92 MB.
  float* qraw = (float*)d_out;

  cast_bf16_kernel<<<(MT * HIDDEN / 4) / 256, 256, 0, stream>>>(hidden, hb, MT * HIDDEN / 4);
  dim3 tb(32, 8);
  transpose_bf16_kernel<<<dim3(64, 64), tb, 0, stream>>>(Wq, wqt, 2048, 2048);
  transpose_bf16_kernel<<<dim3(16, 64), tb, 0, stream>>>(Wk, wkt, 2048, 512);
  transpose_bf16_kernel<<<dim3(16, 64), tb, 0, stream>>>(Wv, wvt, 2048, 512);
  transpose_bf16_kernel<<<dim3(64, 64), tb, 0, stream>>>(Wo, wot, 2048, 2048);

  gemm_bf16_kernel<<<dim3(MT / 128, 16), 256, 0, stream>>>(hb, wqt, qraw, MT, 2048, 2048);
  gemm_bf16_kernel<<<dim3(MT / 128, 4), 256, 0, stream>>>(hb, wkt, kraw, MT, 512, 2048);
  gemm_bf16_kernel<<<dim3(MT / 128, 4), 256, 0, stream>>>(hb, wvt, vraw, MT, 512, 2048);

  norm_rope_kernel<<<MT * NH / 4, 256, 0, stream>>>(qraw, qw, cosb, sinb, Qb, NH);
  norm_rope_kernel<<<MT * NKV / 4, 256, 0, stream>>>(kraw, kw, cosb, sinb, Kbb, NKV);
  v_transpose_kernel<<<dim3(HD / 32, SEQ / 32, NB * NKV), tb, 0, stream>>>(vraw, Vtb);

  attn_kernel<<<(SEQ / 128) * 32, 256, 0, stream>>>(Qb, Kbb, Vtb, Ob);

  gemm_bf16_kernel<<<dim3(MT / 128, 16), 256, 0, stream>>>(Ob, wot, (float*)d_out, MT, 2048, 2048);
}

// Round 6
// 359.928 us; speedup vs baseline: 1.2738x; 1.2738x over previous
//
#include <hip/hip_runtime.h>

typedef float floatx4 __attribute__((ext_vector_type(4)));
typedef short short8 __attribute__((ext_vector_type(8)));

#define HIDDEN 2048
#define NH 16
#define NKV 4
#define HD 128
#define NB 2
#define SEQ 2048
#define MT (NB * SEQ)  // 4096
#define NQKV 3072      // fused projection width: 2048 Q + 512 K + 512 V

__device__ __forceinline__ unsigned short f2bf(float x) {
  union { float f; unsigned u; } v; v.f = x;
  unsigned r = v.u + 0x7FFFu + ((v.u >> 16) & 1u);  // RNE
  return (unsigned short)(r >> 16);
}

// ---------------- contiguous fp32 -> bf16 cast ----------------
__global__ void cast_bf16_kernel(const float* __restrict__ in,
                                 unsigned short* __restrict__ out, int n4) {
  int i = blockIdx.x * 256 + threadIdx.x;
  if (i >= n4) return;
  float4 v = ((const float4*)in)[i];
  ushort4 o;
  o.x = f2bf(v.x); o.y = f2bf(v.y); o.z = f2bf(v.z); o.w = f2bf(v.w);
  ((ushort4*)out)[i] = o;
}

// ------- fused weight transpose + cast -------
// z=0: Wq[2048][2048] -> wqkvt rows 0..2047
// z=1: Wo[2048][2048] -> wot rows 0..2047
// z=2: Wk[2048][512] -> wqkvt rows 2048..2559 ; Wv -> rows 2560..3071
__global__ void wtrans_kernel(const float* __restrict__ Wq,
                              const float* __restrict__ Wk,
                              const float* __restrict__ Wv,
                              const float* __restrict__ Wo,
                              unsigned short* __restrict__ wqkvt,
                              unsigned short* __restrict__ wot) {
  __shared__ float tile[32][33];
  int z = blockIdx.z;
  int nt = blockIdx.x * 32;  // dst-row tile base (source col)
  int k0 = blockIdx.y * 32;
  const float* src;
  unsigned short* dst;
  int Nd, scol0, drow0;
  if (z == 0) {
    src = Wq; Nd = 2048; scol0 = nt; drow0 = nt; dst = wqkvt;
  } else if (z == 1) {
    src = Wo; Nd = 2048; scol0 = nt; drow0 = nt; dst = wot;
  } else {
    if (nt >= 1024) return;
    Nd = 512; dst = wqkvt; drow0 = 2048 + nt;
    if (nt < 512) { src = Wk; scol0 = nt; }
    else          { src = Wv; scol0 = nt - 512; }
  }
  int tx = threadIdx.x, ty = threadIdx.y;
  for (int i = 0; i < 32; i += 8)
    tile[ty + i][tx] = src[(size_t)(k0 + ty + i) * Nd + scol0 + tx];
  __syncthreads();
  for (int i = 0; i < 32; i += 8)
    dst[(size_t)(drow0 + ty + i) * HIDDEN + k0 + tx] = f2bf(tile[tx][ty + i]);
}

// ------- C[M][N] fp32 = A[M][K] bf16 @ Bt[N][K]^T bf16 -------
// m97 structure: 128x128 tile, BK=32, 4 waves 2x2, 16x16x32 MFMA,
// global_load_lds width-16 staging into UNPADDED [128][32] LDS tiles.
__global__ __launch_bounds__(256, 3)
void gemm_bf16_kernel(const unsigned short* __restrict__ A,
                      const unsigned short* __restrict__ Bt,
                      float* __restrict__ C, int M, int N, int K) {
  __shared__ unsigned short As[128 * 32];
  __shared__ unsigned short Bs[128 * 32];
  const int tid = threadIdx.x;
  const int wave = tid >> 6, lane = tid & 63;
  const int quad = lane >> 4, l16 = lane & 15;
  const int m0 = blockIdx.x * 128, n0 = blockIdx.y * 128;
  const int wm = (wave >> 1) * 64, wn = (wave & 1) * 64;
  const int srow = lane >> 2;
  const int scol = (lane & 3) * 8;

  floatx4 acc[4][4] = {};

  for (int kt = 0; kt < K; kt += 32) {
    __syncthreads();
#pragma unroll
    for (int t = 0; t < 2; ++t) {
      int q = wave * 2 + t;
      int row = q * 16 + srow;
      __builtin_amdgcn_global_load_lds(
          (const __attribute__((address_space(1))) unsigned int*)&A[(size_t)(m0 + row) * K + kt + scol],
          (__attribute__((address_space(3))) unsigned int*)&As[q * 16 * 32],
          16, 0, 0);
      __builtin_amdgcn_global_load_lds(
          (const __attribute__((address_space(1))) unsigned int*)&Bt[(size_t)(n0 + row) * K + kt + scol],
          (__attribute__((address_space(3))) unsigned int*)&Bs[q * 16 * 32],
          16, 0, 0);
    }
    __syncthreads();
    short8 af[4], bf[4];
#pragma unroll
    for (int i = 0; i < 4; i++)
      af[i] = *(const short8*)&As[(wm + i * 16 + l16) * 32 + quad * 8];
#pragma unroll
    for (int j = 0; j < 4; j++)
      bf[j] = *(const short8*)&Bs[(wn + j * 16 + l16) * 32 + quad * 8];
#pragma unroll
    for (int i = 0; i < 4; i++)
#pragma unroll
      for (int j = 0; j < 4; j++)
        acc[i][j] = __builtin_amdgcn_mfma_f32_16x16x32_bf16(af[i], bf[j], acc[i][j], 0, 0, 0);
  }
#pragma unroll
  for (int i = 0; i < 4; i++) {
    int row = m0 + wm + i * 16 + quad * 4;
#pragma unroll
    for (int j = 0; j < 4; j++) {
      int col = n0 + wn + j * 16 + l16;
#pragma unroll
      for (int r = 0; r < 4; r++)
        C[(size_t)(row + r) * N + col] = acc[i][j][r];
    }
  }
}

// ------- fused per-head RMSNorm + RoPE + cast for Q and K -------
// X = qkvraw[MT][3072]; 20 logical heads/row: hh<16 -> Q head, else K head.
__global__ void norm_rope_kernel(const float* __restrict__ X,
                                 const float* __restrict__ qw,
                                 const float* __restrict__ kw,
                                 const float* __restrict__ cosb,
                                 const float* __restrict__ sinb,
                                 unsigned short* __restrict__ Qb,   // [NB][NH][SEQ][HD]
                                 unsigned short* __restrict__ Kbb)  // [NB][NKV][SEQ][HD]
{
  int rid = blockIdx.x * 4 + (threadIdx.x >> 6);
  int lane = threadIdx.x & 63;
  int m = rid / 20, hh = rid - m * 20;
  int b = m / SEQ, s = m - b * SEQ;
  const float* w;
  const float* x;
  unsigned short* op;
  if (hh < NH) {
    x = X + (size_t)m * NQKV + hh * HD;
    w = qw;
    op = Qb + (size_t)((b * NH + hh) * SEQ + s) * HD;
  } else {
    int hk = hh - NH;
    x = X + (size_t)m * NQKV + 2048 + hk * HD;
    w = kw;
    op = Kbb + (size_t)((b * NKV + hk) * SEQ + s) * HD;
  }
  float x0 = x[lane], x1 = x[lane + 64];
  float ssq = x0 * x0 + x1 * x1;
#pragma unroll
  for (int off = 32; off >= 1; off >>= 1) ssq += __shfl_xor(ssq, off, 64);
  float rr = rsqrtf(ssq * (1.0f / 128.0f) + 1e-6f);
  float xn0 = x0 * rr * w[lane];
  float xn1 = x1 * rr * w[lane + 64];
  float c0 = cosb[s * HD + lane], c1 = cosb[s * HD + lane + 64];
  float s0 = sinb[s * HD + lane], s1 = sinb[s * HD + lane + 64];
  op[lane] = f2bf(xn0 * c0 - xn1 * s0);       // d < 64:  x*c - x[d+64]*s
  op[lane + 64] = f2bf(xn1 * c1 + xn0 * s1);  // d >= 64: x*c + x[d-64]*s
}

// ------- V transpose + cast: qkvraw[MT][3072] cols 2560.. -> Vt[NB][NKV][HD][SEQ] bf16 -------
__global__ void v_transpose_kernel(const float* __restrict__ X,
                                   unsigned short* __restrict__ Vt) {
  __shared__ float tile[32][33];
  int d0 = blockIdx.x * 32;   // 4 blocks over HD
  int s0 = blockIdx.y * 32;   // 64 blocks over SEQ
  int bkv = blockIdx.z;       // 8: b*NKV+kv
  int b = bkv >> 2, kv = bkv & 3;
  int tx = threadIdx.x, ty = threadIdx.y;
  const float* src = X + (size_t)(b * SEQ + s0) * NQKV + 2560 + kv * HD + d0;
  for (int i = 0; i < 32; i += 8)
    tile[ty + i][tx] = src[(size_t)(ty + i) * NQKV + tx];  // coalesced over d
  __syncthreads();
  unsigned short* dst = Vt + (size_t)(bkv * HD + d0) * SEQ + s0;
  for (int i = 0; i < 32; i += 8)
    dst[(size_t)(ty + i) * SEQ + tx] = f2bf(tile[tx][ty + i]);   // coalesced over s
}

// ------- flash attention, GQA, causal (R4 version: 64-q tiles, 1024 blocks, LPT) -------
#define LQ 136  // LDS stride for [*][128] bf16 tiles (272B rows, 2-way alias = free)

__global__ __launch_bounds__(256, 2)
void attn_kernel(const unsigned short* __restrict__ Q,   // [NB][NH][SEQ][HD]
                 const unsigned short* __restrict__ Kb,  // [NB][NKV][SEQ][HD]
                 const unsigned short* __restrict__ Vt,  // [NB][NKV][HD][SEQ]
                 unsigned short* __restrict__ O) {       // [MT][NH*HD]
  __shared__ unsigned short Qs[64 * LQ];    // 17408 B
  __shared__ unsigned short KVs[128 * LQ];  // 34816 B: K-tile [kv=128][d=128] / V-tile [d=128][kv=128]
  __shared__ unsigned short Ps[64 * LQ];    // 17408 B: P [q=64][kv=128]
  const int tid = threadIdx.x;
  const int wave = tid >> 6, lane = tid & 63;
  const int quad = lane >> 4, l16 = lane & 15;
  // LPT: qt descending with blockIdx.x so longest blocks dispatch first
  const int qt = (SEQ / 64 - 1) - (blockIdx.x >> 5);
  const int bh = blockIdx.x & 31;
  const int b = bh >> 4, h = bh & 15, kvh = h >> 2;
  const int q0 = qt * 64;
  const int nkt = (qt >> 1) + 1;  // number of 128-wide kv tiles

  // stage Q tile: 64 rows x 128 bf16 = 1024 x 16B
  const unsigned short* Qg = Q + (size_t)((b * NH + h) * SEQ + q0) * HD;
  for (int c = tid; c < 1024; c += 256) {
    int r = c >> 4, c8 = c & 15;
    *(uint4*)&Qs[r * LQ + c8 * 8] = *(const uint4*)&Qg[r * HD + c8 * 8];
  }

  floatx4 oacc[8] = {};
  float mrow[4] = {-1e30f, -1e30f, -1e30f, -1e30f};
  float lrow[4] = {0.f, 0.f, 0.f, 0.f};
  const float scale = 0.08838834764831845f;  // 1/sqrt(128)
  const unsigned short* Kg0 = Kb + (size_t)((b * NKV + kvh) * SEQ) * HD;
  const unsigned short* Vg0 = Vt + (size_t)((b * NKV + kvh) * HD) * SEQ;

  for (int kt = 0; kt < nkt; ++kt) {
    __syncthreads();  // prev PV reads done (and Q staged, first iter)
    for (int c = tid; c < 2048; c += 256) {
      int r = c >> 4, c8 = c & 15;
      *(uint4*)&KVs[r * LQ + c8 * 8] = *(const uint4*)&Kg0[(size_t)(kt * 128 + r) * HD + c8 * 8];
    }
    __syncthreads();
    // S = Q @ K^T : wave rows wave*16.., cols 0..127
    floatx4 sc[8] = {};
#pragma unroll
    for (int ks = 0; ks < 4; ++ks) {
      short8 af = *(const short8*)&Qs[(wave * 16 + l16) * LQ + ks * 32 + quad * 8];
#pragma unroll
      for (int j = 0; j < 8; ++j) {
        short8 bf = *(const short8*)&KVs[(j * 16 + l16) * LQ + ks * 32 + quad * 8];
        sc[j] = __builtin_amdgcn_mfma_f32_16x16x32_bf16(af, bf, sc[j], 0, 0, 0);
      }
    }
#pragma unroll
    for (int j = 0; j < 8; ++j)
#pragma unroll
      for (int r = 0; r < 4; ++r) sc[j][r] *= scale;
    if (kt == nkt - 1) {  // only the last tile can contain masked columns
      int rowg = q0 + wave * 16 + quad * 4;
#pragma unroll
      for (int j = 0; j < 8; ++j) {
        int col = kt * 128 + j * 16 + l16;
#pragma unroll
        for (int r = 0; r < 4; ++r)
          if (col > rowg + r) sc[j][r] = -1e30f;
      }
    }
    // online softmax; row r lives in this 16-lane group
    float alpha[4];
#pragma unroll
    for (int r = 0; r < 4; ++r) {
      float mx = sc[0][r];
#pragma unroll
      for (int j = 1; j < 8; ++j) mx = fmaxf(mx, sc[j][r]);
#pragma unroll
      for (int off = 1; off < 16; off <<= 1) mx = fmaxf(mx, __shfl_xor(mx, off, 64));
      float mn = fmaxf(mrow[r], mx);
      alpha[r] = __expf(mrow[r] - mn);
      mrow[r] = mn;
      float rs = 0.f;
#pragma unroll
      for (int j = 0; j < 8; ++j) {
        float p = __expf(sc[j][r] - mn);
        sc[j][r] = p;
        rs += p;
      }
#pragma unroll
      for (int off = 1; off < 16; off <<= 1) rs += __shfl_xor(rs, off, 64);
      lrow[r] = lrow[r] * alpha[r] + rs;
    }
#pragma unroll
    for (int t = 0; t < 8; ++t)
#pragma unroll
      for (int r = 0; r < 4; ++r) oacc[t][r] *= alpha[r];
    // P (C-layout) -> LDS -> A-layout for PV
#pragma unroll
    for (int j = 0; j < 8; ++j)
#pragma unroll
      for (int r = 0; r < 4; ++r)
        Ps[(wave * 16 + quad * 4 + r) * LQ + j * 16 + l16] = f2bf(sc[j][r]);
    __syncthreads();  // all waves' K reads done before V overwrites KVs
    // stage V tile as [d=128][kv=128] = 2048 x 16B
    for (int c = tid; c < 2048; c += 256) {
      int d = c >> 4, c8 = c & 15;
      *(uint4*)&KVs[d * LQ + c8 * 8] = *(const uint4*)&Vg0[(size_t)d * SEQ + kt * 128 + c8 * 8];
    }
    __syncthreads();
    // O += P @ V  (kv is the K-dim, 128 = 4 x 32)
#pragma unroll
    for (int ks = 0; ks < 4; ++ks) {
      short8 af = *(const short8*)&Ps[(wave * 16 + l16) * LQ + ks * 32 + quad * 8];
#pragma unroll
      for (int t = 0; t < 8; ++t) {
        short8 bf = *(const short8*)&KVs[(t * 16 + l16) * LQ + ks * 32 + quad * 8];
        oacc[t] = __builtin_amdgcn_mfma_f32_16x16x32_bf16(af, bf, oacc[t], 0, 0, 0);
      }
    }
  }
  float inv[4];
#pragma unroll
  for (int r = 0; r < 4; ++r) inv[r] = 1.0f / lrow[r];
#pragma unroll
  for (int t = 0; t < 8; ++t) {
    int col = h * HD + t * 16 + l16;
#pragma unroll
    for (int r = 0; r < 4; ++r) {
      int row = q0 + wave * 16 + quad * 4 + r;
      O[(size_t)(b * SEQ + row) * (NH * HD) + col] = f2bf(oacc[t][r] * inv[r]);
    }
  }
}

extern "C" void kernel_launch(void* const* d_in, const int* in_sizes, int n_in,
                              void* d_out, int out_size, void* d_ws, size_t ws_size,
                              hipStream_t stream) {
  const float* hidden = (const float*)d_in[0];
  const float* cosb   = (const float*)d_in[1];
  const float* sinb   = (const float*)d_in[2];
  const float* Wq     = (const float*)d_in[3];
  const float* Wk     = (const float*)d_in[4];
  const float* Wv     = (const float*)d_in[5];
  const float* Wo     = (const float*)d_in[6];
  const float* qw     = (const float*)d_in[7];
  const float* kw     = (const float*)d_in[8];
  (void)in_sizes; (void)n_in; (void)out_size; (void)ws_size;

  char* ws = (char*)d_ws;
  size_t off = 0;
  auto alloc = [&](size_t n) { char* p = ws + off; off += (n + 255) & ~(size_t)255; return p; };

  unsigned short* hb    = (unsigned short*)alloc((size_t)MT * HIDDEN * 2);   // hidden bf16 (16 MB)
  unsigned short* wqkvt = (unsigned short*)alloc((size_t)NQKV * HIDDEN * 2); // Wqkv^T bf16 (12 MB)
  unsigned short* wot   = (unsigned short*)alloc((size_t)2048 * 2048 * 2);   // (8 MB)
  float* qkvraw = (float*)alloc((size_t)MT * NQKV * 4);                      // (48 MB)
  unsigned short* Qb  = (unsigned short*)alloc((size_t)MT * 2048 * 2);  // [NB][NH][SEQ][HD] (16 MB)
  unsigned short* Kbb = (unsigned short*)alloc((size_t)MT * 512 * 2);   // [NB][NKV][SEQ][HD] (4 MB)
  unsigned short* Vtb = (unsigned short*)alloc((size_t)MT * 512 * 2);   // [NB][NKV][HD][SEQ] (4 MB)
  unsigned short* Ob  = (unsigned short*)alloc((size_t)MT * 2048 * 2);  // attn out (16 MB)
  // total ~124 MB

  cast_bf16_kernel<<<(MT * HIDDEN / 4) / 256, 256, 0, stream>>>(hidden, hb, MT * HIDDEN / 4);
  dim3 tb(32, 8);
  wtrans_kernel<<<dim3(64, 64, 3), tb, 0, stream>>>(Wq, Wk, Wv, Wo, wqkvt, wot);

  // fused QKV projection: [4096 x 3072] = hb @ wqkvt^T ; grid 32x24 = 768 = 256 CU x 3
  gemm_bf16_kernel<<<dim3(MT / 128, NQKV / 128), 256, 0, stream>>>(hb, wqkvt, qkvraw, MT, NQKV, HIDDEN);

  norm_rope_kernel<<<MT * (NH + NKV) / 4, 256, 0, stream>>>(qkvraw, qw, kw, cosb, sinb, Qb, Kbb);
  v_transpose_kernel<<<dim3(HD / 32, SEQ / 32, NB * NKV), tb, 0, stream>>>(qkvraw, Vtb);

  attn_kernel<<<(SEQ / 64) * 32, 256, 0, stream>>>(Qb, Kbb, Vtb, Ob);

  gemm_bf16_kernel<<<dim3(MT / 128, 16), 256, 0, stream>>>(Ob, wot, (float*)d_out, MT, 2048, 2048);
}

// Round 7
// 345.806 us; speedup vs baseline: 1.3259x; 1.0408x over previous
//
#include <hip/hip_runtime.h>

typedef float floatx4 __attribute__((ext_vector_type(4)));
typedef short short8 __attribute__((ext_vector_type(8)));

#define HIDDEN 2048
#define NH 16
#define NKV 4
#define HD 128
#define NB 2
#define SEQ 2048
#define MT (NB * SEQ)  // 4096
#define NQKV 3072      // fused projection width: 2048 Q + 512 K + 512 V

__device__ __forceinline__ unsigned short f2bf(float x) {
  union { float f; unsigned u; } v; v.f = x;
  unsigned r = v.u + 0x7FFFu + ((v.u >> 16) & 1u);  // RNE
  return (unsigned short)(r >> 16);
}

// ---------------- contiguous fp32 -> bf16 cast ----------------
__global__ void cast_bf16_kernel(const float* __restrict__ in,
                                 unsigned short* __restrict__ out, int n4) {
  int i = blockIdx.x * 256 + threadIdx.x;
  if (i >= n4) return;
  float4 v = ((const float4*)in)[i];
  ushort4 o;
  o.x = f2bf(v.x); o.y = f2bf(v.y); o.z = f2bf(v.z); o.w = f2bf(v.w);
  ((ushort4*)out)[i] = o;
}

// ------- fused weight transpose + cast -------
// z=0: Wq -> wqkvt rows 0..2047 ; z=1: Wo -> wot ; z=2: Wk -> rows 2048.., Wv -> rows 2560..
__global__ void wtrans_kernel(const float* __restrict__ Wq,
                              const float* __restrict__ Wk,
                              const float* __restrict__ Wv,
                              const float* __restrict__ Wo,
                              unsigned short* __restrict__ wqkvt,
                              unsigned short* __restrict__ wot) {
  __shared__ float tile[32][33];
  int z = blockIdx.z;
  int nt = blockIdx.x * 32;
  int k0 = blockIdx.y * 32;
  const float* src;
  unsigned short* dst;
  int Nd, scol0, drow0;
  if (z == 0) {
    src = Wq; Nd = 2048; scol0 = nt; drow0 = nt; dst = wqkvt;
  } else if (z == 1) {
    src = Wo; Nd = 2048; scol0 = nt; drow0 = nt; dst = wot;
  } else {
    if (nt >= 1024) return;
    Nd = 512; dst = wqkvt; drow0 = 2048 + nt;
    if (nt < 512) { src = Wk; scol0 = nt; }
    else          { src = Wv; scol0 = nt - 512; }
  }
  int tx = threadIdx.x, ty = threadIdx.y;
  for (int i = 0; i < 32; i += 8)
    tile[ty + i][tx] = src[(size_t)(k0 + ty + i) * Nd + scol0 + tx];
  __syncthreads();
  for (int i = 0; i < 32; i += 8)
    dst[(size_t)(drow0 + ty + i) * HIDDEN + k0 + tx] = f2bf(tile[tx][ty + i]);
}

// ------- plain C[M][N] fp32 = A @ Bt^T (m97 structure) — used for O-proj -------
__global__ __launch_bounds__(256, 3)
void gemm_bf16_kernel(const unsigned short* __restrict__ A,
                      const unsigned short* __restrict__ Bt,
                      float* __restrict__ C, int M, int N, int K) {
  __shared__ unsigned short As[128 * 32];
  __shared__ unsigned short Bs[128 * 32];
  const int tid = threadIdx.x;
  const int wave = tid >> 6, lane = tid & 63;
  const int quad = lane >> 4, l16 = lane & 15;
  const int m0 = blockIdx.x * 128, n0 = blockIdx.y * 128;
  const int wm = (wave >> 1) * 64, wn = (wave & 1) * 64;
  const int srow = lane >> 2;
  const int scol = (lane & 3) * 8;

  floatx4 acc[4][4] = {};

  for (int kt = 0; kt < K; kt += 32) {
    __syncthreads();
#pragma unroll
    for (int t = 0; t < 2; ++t) {
      int q = wave * 2 + t;
      int row = q * 16 + srow;
      __builtin_amdgcn_global_load_lds(
          (const __attribute__((address_space(1))) unsigned int*)&A[(size_t)(m0 + row) * K + kt + scol],
          (__attribute__((address_space(3))) unsigned int*)&As[q * 16 * 32],
          16, 0, 0);
      __builtin_amdgcn_global_load_lds(
          (const __attribute__((address_space(1))) unsigned int*)&Bt[(size_t)(n0 + row) * K + kt + scol],
          (__attribute__((address_space(3))) unsigned int*)&Bs[q * 16 * 32],
          16, 0, 0);
    }
    __syncthreads();
    short8 af[4], bf[4];
#pragma unroll
    for (int i = 0; i < 4; i++)
      af[i] = *(const short8*)&As[(wm + i * 16 + l16) * 32 + quad * 8];
#pragma unroll
    for (int j = 0; j < 4; j++)
      bf[j] = *(const short8*)&Bs[(wn + j * 16 + l16) * 32 + quad * 8];
#pragma unroll
    for (int i = 0; i < 4; i++)
#pragma unroll
      for (int j = 0; j < 4; j++)
        acc[i][j] = __builtin_amdgcn_mfma_f32_16x16x32_bf16(af[i], bf[j], acc[i][j], 0, 0, 0);
  }
#pragma unroll
  for (int i = 0; i < 4; i++) {
    int row = m0 + wm + i * 16 + quad * 4;
#pragma unroll
    for (int j = 0; j < 4; j++) {
      int col = n0 + wn + j * 16 + l16;
#pragma unroll
      for (int r = 0; r < 4; r++)
        C[(size_t)(row + r) * N + col] = acc[i][j][r];
    }
  }
}

// ------- QKV GEMM with fused RMSNorm+RoPE (Q/K) and V-transpose epilogue -------
// N-tile (128 cols) == exactly one head. heads 0..15 -> Qb, 16..19 -> Kbb, 20..23 -> Vt.
__global__ __launch_bounds__(256, 3)
void gemm_qkv_kernel(const unsigned short* __restrict__ A,    // hb [MT][2048]
                     const unsigned short* __restrict__ Bt,   // wqkvt [3072][2048]
                     const float* __restrict__ qw,
                     const float* __restrict__ kw,
                     const float* __restrict__ cosb,
                     const float* __restrict__ sinb,
                     unsigned short* __restrict__ Qb,   // [NB][NH][SEQ][HD]
                     unsigned short* __restrict__ Kbb,  // [NB][NKV][SEQ][HD]
                     unsigned short* __restrict__ Vt) { // [NB][NKV][HD][SEQ]
  __shared__ __align__(16) unsigned short As[128 * 32];
  __shared__ __align__(16) unsigned short Bs[128 * 32];
  __shared__ __align__(16) float pscr[4 * 64 * 20];  // [wave][col 64][rows 16+pad] raw acc exchange
  __shared__ float pssq[2][128];                      // [col-half][row] partial ssq
  const int tid = threadIdx.x;
  const int wave = tid >> 6, lane = tid & 63;
  const int quad = lane >> 4, l16 = lane & 15;
  const int m0 = blockIdx.x * 128, n0 = blockIdx.y * 128;
  const int wm = (wave >> 1) * 64, wn = (wave & 1) * 64;
  const int srow = lane >> 2;
  const int scol = (lane & 3) * 8;

  floatx4 acc[4][4] = {};

  for (int kt = 0; kt < HIDDEN; kt += 32) {
    __syncthreads();
#pragma unroll
    for (int t = 0; t < 2; ++t) {
      int q = wave * 2 + t;
      int row = q * 16 + srow;
      __builtin_amdgcn_global_load_lds(
          (const __attribute__((address_space(1))) unsigned int*)&A[(size_t)(m0 + row) * HIDDEN + kt + scol],
          (__attribute__((address_space(3))) unsigned int*)&As[q * 16 * 32],
          16, 0, 0);
      __builtin_amdgcn_global_load_lds(
          (const __attribute__((address_space(1))) unsigned int*)&Bt[(size_t)(n0 + row) * HIDDEN + kt + scol],
          (__attribute__((address_space(3))) unsigned int*)&Bs[q * 16 * 32],
          16, 0, 0);
    }
    __syncthreads();
    short8 af[4], bf[4];
#pragma unroll
    for (int i = 0; i < 4; i++)
      af[i] = *(const short8*)&As[(wm + i * 16 + l16) * 32 + quad * 8];
#pragma unroll
    for (int j = 0; j < 4; j++)
      bf[j] = *(const short8*)&Bs[(wn + j * 16 + l16) * 32 + quad * 8];
#pragma unroll
    for (int i = 0; i < 4; i++)
#pragma unroll
      for (int j = 0; j < 4; j++)
        acc[i][j] = __builtin_amdgcn_mfma_f32_16x16x32_bf16(af[i], bf[j], acc[i][j], 0, 0, 0);
  }

  const int head = n0 >> 7;
  if (head >= NH + NKV) {
    // ---- V path: cast + write transposed Vt[b][kv][d][s] (s packed x4) ----
    const int kv = head - (NH + NKV);
#pragma unroll
    for (int i = 0; i < 4; ++i) {
      int m = m0 + wm + i * 16 + quad * 4;
      int b = m >> 11, sbase = m & (SEQ - 1);
#pragma unroll
      for (int j = 0; j < 4; ++j) {
        int d = wn + j * 16 + l16;
        ushort4 pk;
        pk.x = f2bf(acc[i][j][0]); pk.y = f2bf(acc[i][j][1]);
        pk.z = f2bf(acc[i][j][2]); pk.w = f2bf(acc[i][j][3]);
        *(ushort4*)&Vt[((size_t)(b * NKV + kv) * HD + d) * SEQ + sbase] = pk;
      }
    }
    return;  // head is block-uniform: no barrier divergence
  }

  // ---- Q/K path: RMSNorm (over 128 cols = full head) + RoPE + cast ----
  const float* w = (head < NH) ? qw : kw;
  float wown[4], wpar[4];
#pragma unroll
  for (int j = 0; j < 4; ++j) {
    wown[j] = w[wn + j * 16 + l16];
    wpar[j] = w[(wn ^ 64) + j * 16 + l16];
  }
#pragma unroll
  for (int i = 0; i < 4; ++i) {
    // partial sum-of-squares per row over this wave's 64 cols
    float sq[4];
#pragma unroll
    for (int r = 0; r < 4; ++r) {
      float s2 = acc[i][0][r] * acc[i][0][r] + acc[i][1][r] * acc[i][1][r] +
                 acc[i][2][r] * acc[i][2][r] + acc[i][3][r] * acc[i][3][r];
#pragma unroll
      for (int off = 1; off < 16; off <<= 1) s2 += __shfl_xor(s2, off, 64);
      sq[r] = s2;
    }
    if (l16 == 0)
      *(float4*)&pssq[wn >> 6][wm + i * 16 + quad * 4] = make_float4(sq[0], sq[1], sq[2], sq[3]);
    // publish raw acc for the partner col-half (RoPE needs x[d^64])
#pragma unroll
    for (int j = 0; j < 4; ++j)
      *(float4*)&pscr[(wave * 64 + j * 16 + l16) * 20 + quad * 4] = *(float4*)&acc[i][j];
    __syncthreads();
    float4 oss = *(const float4*)&pssq[(wn >> 6) ^ 1][wm + i * 16 + quad * 4];
    float rr[4];
    rr[0] = rsqrtf((sq[0] + oss.x) * (1.0f / 128.0f) + 1e-6f);
    rr[1] = rsqrtf((sq[1] + oss.y) * (1.0f / 128.0f) + 1e-6f);
    rr[2] = rsqrtf((sq[2] + oss.z) * (1.0f / 128.0f) + 1e-6f);
    rr[3] = rsqrtf((sq[3] + oss.w) * (1.0f / 128.0f) + 1e-6f);
    int mbase = m0 + wm + i * 16 + quad * 4;
    int b = mbase >> 11, sbase = mbase & (SEQ - 1);
#pragma unroll
    for (int j = 0; j < 4; ++j) {
      float4 par = *(const float4*)&pscr[((wave ^ 1) * 64 + j * 16 + l16) * 20 + quad * 4];
      float pr[4] = {par.x, par.y, par.z, par.w};
      int d = wn + j * 16 + l16;
      unsigned short* dst = (head < NH)
          ? Qb + ((size_t)(b * NH + head) * SEQ + sbase) * HD + d
          : Kbb + ((size_t)(b * NKV + (head - NH)) * SEQ + sbase) * HD + d;
#pragma unroll
      for (int r = 0; r < 4; ++r) {
        int s = sbase + r;
        float c = cosb[s * HD + d], sn = sinb[s * HD + d];
        float xo = acc[i][j][r] * rr[r] * wown[j];
        float xp = pr[r] * rr[r] * wpar[j];
        float out = (wn == 0) ? (xo * c - xp * sn) : (xo * c + xp * sn);
        dst[(size_t)r * HD] = f2bf(out);
      }
    }
    __syncthreads();  // pscr/pssq reused next i
  }
}

// ------- flash attention, GQA, causal: 64-q tiles, 1024 blocks, LPT, reg-Q -------
#define LQ 136  // LDS stride for [*][128] bf16 tiles (272B rows, 2-way alias = free)

__global__ __launch_bounds__(256, 3)
void attn_kernel(const unsigned short* __restrict__ Q,   // [NB][NH][SEQ][HD]
                 const unsigned short* __restrict__ Kb,  // [NB][NKV][SEQ][HD]
                 const unsigned short* __restrict__ Vt,  // [NB][NKV][HD][SEQ]
                 unsigned short* __restrict__ O) {       // [MT][NH*HD]
  __shared__ unsigned short KVs[128 * LQ];  // 34816 B: K [kv=128][d=128] / V [d=128][kv=128]
  __shared__ unsigned short Ps[64 * LQ];    // 17408 B: P [q=64][kv=128]
  const int tid = threadIdx.x;
  const int wave = tid >> 6, lane = tid & 63;
  const int quad = lane >> 4, l16 = lane & 15;
  const int qt = (SEQ / 64 - 1) - (blockIdx.x >> 5);  // LPT: longest first
  const int bh = blockIdx.x & 31;
  const int b = bh >> 4, h = bh & 15, kvh = h >> 2;
  const int q0 = qt * 64;
  const int nkt = (qt >> 1) + 1;

  // Q A-fragments live in registers: wave owns rows q0 + wave*16 .. +15
  const unsigned short* Qg = Q + (size_t)((b * NH + h) * SEQ + q0) * HD;
  short8 qf[4];
#pragma unroll
  for (int ks = 0; ks < 4; ++ks)
    qf[ks] = *(const short8*)&Qg[(size_t)(wave * 16 + l16) * HD + ks * 32 + quad * 8];

  floatx4 oacc[8] = {};
  float mrow[4] = {-1e30f, -1e30f, -1e30f, -1e30f};
  float lrow[4] = {0.f, 0.f, 0.f, 0.f};
  const float scale = 0.08838834764831845f;  // 1/sqrt(128)
  const unsigned short* Kg0 = Kb + (size_t)((b * NKV + kvh) * SEQ) * HD;
  const unsigned short* Vg0 = Vt + (size_t)((b * NKV + kvh) * HD) * SEQ;

  for (int kt = 0; kt < nkt; ++kt) {
    __syncthreads();  // prev PV reads of KVs done
    for (int c = tid; c < 2048; c += 256) {
      int r = c >> 4, c8 = c & 15;
      *(uint4*)&KVs[r * LQ + c8 * 8] = *(const uint4*)&Kg0[(size_t)(kt * 128 + r) * HD + c8 * 8];
    }
    __syncthreads();
    // S = Q @ K^T
    floatx4 sc[8] = {};
#pragma unroll
    for (int ks = 0; ks < 4; ++ks) {
#pragma unroll
      for (int j = 0; j < 8; ++j) {
        short8 bf = *(const short8*)&KVs[(j * 16 + l16) * LQ + ks * 32 + quad * 8];
        sc[j] = __builtin_amdgcn_mfma_f32_16x16x32_bf16(qf[ks], bf, sc[j], 0, 0, 0);
      }
    }
#pragma unroll
    for (int j = 0; j < 8; ++j)
#pragma unroll
      for (int r = 0; r < 4; ++r) sc[j][r] *= scale;
    if (kt == nkt - 1) {
      int rowg = q0 + wave * 16 + quad * 4;
#pragma unroll
      for (int j = 0; j < 8; ++j) {
        int col = kt * 128 + j * 16 + l16;
#pragma unroll
        for (int r = 0; r < 4; ++r)
          if (col > rowg + r) sc[j][r] = -1e30f;
      }
    }
    float alpha[4];
#pragma unroll
    for (int r = 0; r < 4; ++r) {
      float mx = sc[0][r];
#pragma unroll
      for (int j = 1; j < 8; ++j) mx = fmaxf(mx, sc[j][r]);
#pragma unroll
      for (int off = 1; off < 16; off <<= 1) mx = fmaxf(mx, __shfl_xor(mx, off, 64));
      float mn = fmaxf(mrow[r], mx);
      alpha[r] = __expf(mrow[r] - mn);
      mrow[r] = mn;
      float rs = 0.f;
#pragma unroll
      for (int j = 0; j < 8; ++j) {
        float p = __expf(sc[j][r] - mn);
        sc[j][r] = p;
        rs += p;
      }
#pragma unroll
      for (int off = 1; off < 16; off <<= 1) rs += __shfl_xor(rs, off, 64);
      lrow[r] = lrow[r] * alpha[r] + rs;
    }
#pragma unroll
    for (int t = 0; t < 8; ++t)
#pragma unroll
      for (int r = 0; r < 4; ++r) oacc[t][r] *= alpha[r];
#pragma unroll
    for (int j = 0; j < 8; ++j)
#pragma unroll
      for (int r = 0; r < 4; ++r)
        Ps[(wave * 16 + quad * 4 + r) * LQ + j * 16 + l16] = f2bf(sc[j][r]);
    __syncthreads();  // K reads done before V overwrites KVs
    for (int c = tid; c < 2048; c += 256) {
      int d = c >> 4, c8 = c & 15;
      *(uint4*)&KVs[d * LQ + c8 * 8] = *(const uint4*)&Vg0[(size_t)d * SEQ + kt * 128 + c8 * 8];
    }
    __syncthreads();
#pragma unroll
    for (int ks = 0; ks < 4; ++ks) {
      short8 af = *(const short8*)&Ps[(wave * 16 + l16) * LQ + ks * 32 + quad * 8];
#pragma unroll
      for (int t = 0; t < 8; ++t) {
        short8 bf = *(const short8*)&KVs[(t * 16 + l16) * LQ + ks * 32 + quad * 8];
        oacc[t] = __builtin_amdgcn_mfma_f32_16x16x32_bf16(af, bf, oacc[t], 0, 0, 0);
      }
    }
  }
  float inv[4];
#pragma unroll
  for (int r = 0; r < 4; ++r) inv[r] = 1.0f / lrow[r];
#pragma unroll
  for (int t = 0; t < 8; ++t) {
    int col = h * HD + t * 16 + l16;
#pragma unroll
    for (int r = 0; r < 4; ++r) {
      int row = q0 + wave * 16 + quad * 4 + r;
      O[(size_t)(b * SEQ + row) * (NH * HD) + col] = f2bf(oacc[t][r] * inv[r]);
    }
  }
}

extern "C" void kernel_launch(void* const* d_in, const int* in_sizes, int n_in,
                              void* d_out, int out_size, void* d_ws, size_t ws_size,
                              hipStream_t stream) {
  const float* hidden = (const float*)d_in[0];
  const float* cosb   = (const float*)d_in[1];
  const float* sinb   = (const float*)d_in[2];
  const float* Wq     = (const float*)d_in[3];
  const float* Wk     = (const float*)d_in[4];
  const float* Wv     = (const float*)d_in[5];
  const float* Wo     = (const float*)d_in[6];
  const float* qw     = (const float*)d_in[7];
  const float* kw     = (const float*)d_in[8];
  (void)in_sizes; (void)n_in; (void)out_size; (void)ws_size;

  char* ws = (char*)d_ws;
  size_t off = 0;
  auto alloc = [&](size_t n) { char* p = ws + off; off += (n + 255) & ~(size_t)255; return p; };

  unsigned short* hb    = (unsigned short*)alloc((size_t)MT * HIDDEN * 2);   // (16 MB)
  unsigned short* wqkvt = (unsigned short*)alloc((size_t)NQKV * HIDDEN * 2); // (12 MB)
  unsigned short* wot   = (unsigned short*)alloc((size_t)2048 * 2048 * 2);   // (8 MB)
  unsigned short* Qb  = (unsigned short*)alloc((size_t)MT * 2048 * 2);  // [NB][NH][SEQ][HD] (16 MB)
  unsigned short* Kbb = (unsigned short*)alloc((size_t)MT * 512 * 2);   // [NB][NKV][SEQ][HD] (4 MB)
  unsigned short* Vtb = (unsigned short*)alloc((size_t)MT * 512 * 2);   // [NB][NKV][HD][SEQ] (4 MB)
  unsigned short* Ob  = (unsigned short*)alloc((size_t)MT * 2048 * 2);  // attn out (16 MB)
  // total ~76 MB

  cast_bf16_kernel<<<(MT * HIDDEN / 4) / 256, 256, 0, stream>>>(hidden, hb, MT * HIDDEN / 4);
  dim3 tb(32, 8);
  wtrans_kernel<<<dim3(64, 64, 3), tb, 0, stream>>>(Wq, Wk, Wv, Wo, wqkvt, wot);

  // fused QKV projection + norm/rope/V-transpose epilogue: grid 32x24 = 768 blocks
  gemm_qkv_kernel<<<dim3(MT / 128, NQKV / 128), 256, 0, stream>>>(
      hb, wqkvt, qw, kw, cosb, sinb, Qb, Kbb, Vtb);

  attn_kernel<<<(SEQ / 64) * 32, 256, 0, stream>>>(Qb, Kbb, Vtb, Ob);

  gemm_bf16_kernel<<<dim3(MT / 128, 16), 256, 0, stream>>>(Ob, wot, (float*)d_out, MT, 2048, 2048);
}